// Round 10
// baseline (149.142 us; speedup 1.0000x reference)
//
#include <hip/hip_runtime.h>
#include <hip/hip_bf16.h>

#define BB 2
#define CC 256
#define HEADS 8
#define HD 32
#define LL 4096
#define HALF_WIN 512

using short8  = __attribute__((ext_vector_type(8))) short;
using short4v = __attribute__((ext_vector_type(4))) short;
using float4v = __attribute__((ext_vector_type(4))) float;

__device__ __forceinline__ ushort f2bf(float x) {
    uint u = __float_as_uint(x);
    u += 0x7fff + ((u >> 16) & 1);
    return (ushort)(u >> 16);
}
__device__ __forceinline__ float ubf(ushort u) {
    return __uint_as_float((uint)u << 16);
}
// packed f32x2 -> bf16x2 (lo = first arg), HW instr on gfx950
__device__ __forceinline__ uint pk2bf(float a, float b) {
#if __has_builtin(__builtin_amdgcn_cvt_pk_bf16_f32)
    typedef __bf16 v2bf __attribute__((ext_vector_type(2)));
    union { v2bf v; uint u; } cv;
    cv.v = __builtin_amdgcn_cvt_pk_bf16_f32(a, b);
    return cv.u;
#else
    return (uint)f2bf(a) | ((uint)f2bf(b) << 16);
#endif
}
// raw v_exp_f32 (no OCML wrapper/fixup)
__device__ __forceinline__ float rexp2(float x) {
#if __has_builtin(__builtin_amdgcn_exp2f)
    return __builtin_amdgcn_exp2f(x);
#else
    return exp2f(x);
#endif
}

// q is pre-scaled by (1/sqrt(32)) * log2(e) so attention uses exp2 directly
#define QSCALE 0.25503485f

// ---------------- Kernel 0: weight transpose + bf16 (w1 and w2) --------------
__global__ __launch_bounds__(256) void wt_kernel(const float* __restrict__ w1,
                                                 const float* __restrict__ w2,
                                                 ushort* __restrict__ w1t,
                                                 ushort* __restrict__ w2t) {
    __shared__ float tl[16][17];
    const int tx = threadIdx.x & 15, ty = threadIdx.x >> 4;
    const int ci0 = blockIdx.x * 16;
    const int y = blockIdx.y;
    if (y < 48) {
        int j0 = y * 16;
        tl[ty][tx] = w1[(size_t)(ci0 + ty) * 768 + j0 + tx];
        __syncthreads();
        w1t[(size_t)(j0 + ty) * CC + ci0 + tx] = f2bf(tl[tx][ty]);
    } else {
        int co0 = (y - 48) * 16;
        tl[ty][tx] = w2[(size_t)(ci0 + ty) * CC + co0 + tx];
        __syncthreads();
        w2t[(size_t)(co0 + ty) * CC + ci0 + tx] = f2bf(tl[tx][ty]);
    }
}

// ---------------- Kernel 1: QKV projection (MFMA) ----------------------------
__global__ __launch_bounds__(256) void qkv_kernel(const float* __restrict__ x,
                                                  const ushort* __restrict__ w1t,
                                                  const float* __restrict__ b1,
                                                  ushort* __restrict__ qb,
                                                  ushort* __restrict__ kb,
                                                  ushort* __restrict__ vt) {
    __shared__ __align__(16) ushort xs[64 * 264];  // [l][c]; reused in epilogue
    const int dg = blockIdx.x;
    const int l0 = blockIdx.y * 64;
    const int b  = blockIdx.z;
    const int t  = threadIdx.x;
    const int w  = t >> 6, ln = t & 63, c = ln & 15, g = ln >> 4;

    {
        const int l  = t & 63;
        const int cg = (t >> 6) * 4;
#pragma unroll
        for (int p = 0; p < 16; p++) {
            int c0 = p * 16 + cg;
            float a0 = x[((size_t)b * CC + c0 + 0) * LL + l0 + l];
            float a1 = x[((size_t)b * CC + c0 + 1) * LL + l0 + l];
            float a2 = x[((size_t)b * CC + c0 + 2) * LL + l0 + l];
            float a3 = x[((size_t)b * CC + c0 + 3) * LL + l0 + l];
            uint2 u;
            u.x = pk2bf(a0, a1);
            u.y = pk2bf(a2, a3);
            *(uint2*)&xs[l * 264 + c0] = u;
        }
    }
    __syncthreads();

    const int jbase = dg * 192 + w * 48;
    float4v acc[3][4] = {};
#pragma unroll
    for (int ks = 0; ks < 8; ks++) {
        short8 af[3], bfr[4];
#pragma unroll
        for (int jt = 0; jt < 3; jt++)
            af[jt] = *(const short8*)(w1t + (size_t)(jbase + jt * 16 + c) * CC + ks * 32 + g * 8);
#pragma unroll
        for (int lt = 0; lt < 4; lt++)
            bfr[lt] = *(const short8*)&xs[(lt * 16 + c) * 264 + ks * 32 + g * 8];
#pragma unroll
        for (int jt = 0; jt < 3; jt++)
#pragma unroll
            for (int lt = 0; lt < 4; lt++)
                acc[jt][lt] = __builtin_amdgcn_mfma_f32_16x16x32_bf16(af[jt], bfr[lt], acc[jt][lt], 0, 0, 0);
    }
    __syncthreads();

    ushort* qs  = xs;
    ushort* ksm = xs + 64 * 72;
    ushort* vs  = xs + 2 * 64 * 72;

#pragma unroll
    for (int jt = 0; jt < 3; jt++) {
#pragma unroll
        for (int r = 0; r < 4; r++) {
            int j = jbase + jt * 16 + g * 4 + r;
            float bias = b1[j];
            int t3 = j % 3, h = (j / 3) & 7, dl = (j / 24) & 7;
            int slot = h * 8 + dl;
            float v0 = acc[jt][0][r] + bias;
            float v1 = acc[jt][1][r] + bias;
            float v2 = acc[jt][2][r] + bias;
            float v3 = acc[jt][3][r] + bias;
            if (t3 == 0) { v0 *= QSCALE; v1 *= QSCALE; v2 *= QSCALE; v3 *= QSCALE; }
            uint u01 = pk2bf(v0, v1);
            uint u23 = pk2bf(v2, v3);
            ushort* dst = (t3 == 0) ? qs : (t3 == 1) ? ksm : vs;
            int stride = (t3 == 2) ? 74 : 72;
            dst[(0 * 16 + c) * stride + slot] = (ushort)u01;
            dst[(1 * 16 + c) * stride + slot] = (ushort)(u01 >> 16);
            dst[(2 * 16 + c) * stride + slot] = (ushort)u23;
            dst[(3 * 16 + c) * stride + slot] = (ushort)(u23 >> 16);
        }
    }
    __syncthreads();

    {
        const int l = t & 63;
#pragma unroll
        for (int p = 0; p < 2; p++) {
            int h = p * 4 + (t >> 6);
            size_t rowq = (((size_t)(b * 8 + h) * 4 + dg) * LL + l0 + l) * 8;
            *(short8*)(qb + rowq) = *(const short8*)&qs[l * 72 + h * 8];
            *(short8*)(kb + rowq) = *(const short8*)&ksm[l * 72 + h * 8];
        }
#pragma unroll
        for (int p = 0; p < 16; p++) {
            int hd = p * 4 + (t >> 6);
            vt[((size_t)(b * 8 + (hd >> 3)) * HD + dg * 8 + (hd & 7)) * LL + l0 + l] = vs[l * 74 + hd];
        }
    }
}

__device__ __forceinline__ int gcol_of(int tt) {
    return (tt == 0) ? 0 : (tt == 3) ? 63 : (tt == 252) ? LL - 64 : (tt == 255) ? LL - 1 : -1;
}

// Assemble PV B-fragment (P^T[j][i=c], k=j 0..31 of the pair) from packed
// pA (ua) / pB (ub) via cross-lane shuffles. Lanes {c,c+16,c+32,c+48} exchange.
__device__ __forceinline__ short8 ptrans(uint2 ua, uint2 ub, int c, int g) {
    const int laneL = c + ((g & 1) << 5);
    const int laneH = laneL + 16;
    int a0 = __shfl((int)ua.x, laneL);
    int a1 = __shfl((int)ua.y, laneL);
    int a2 = __shfl((int)ua.x, laneH);
    int a3 = __shfl((int)ua.y, laneH);
    int b0 = __shfl((int)ub.x, laneL);
    int b1 = __shfl((int)ub.y, laneL);
    int b2 = __shfl((int)ub.x, laneH);
    int b3 = __shfl((int)ub.y, laneH);
    union { uint u[4]; short8 s8; } pf;
    bool lo = (g < 2);
    pf.u[0] = lo ? (uint)a0 : (uint)b0;
    pf.u[1] = lo ? (uint)a1 : (uint)b1;
    pf.u[2] = lo ? (uint)a2 : (uint)b2;
    pf.u[3] = lo ? (uint)a3 : (uint)b3;
    return pf.s8;
}

// ---------------- Kernel 2: banded MFMA attention (zero-LDS) -----------------
// S^T = mfma(K,Q); P packed to bf16, transposed in-register via shuffles;
// PV computed as O^T = V^T . P^T (V frags load directly from vt layout).
__global__ __launch_bounds__(256) void attn_kernel(const ushort* __restrict__ qb,
                                                   const ushort* __restrict__ kb,
                                                   const ushort* __restrict__ vt,
                                                   ushort* __restrict__ obuf) {
    const int n  = blockIdx.x;
    const int bh = ((n & 7) << 1) | ((n >> 3) & 1);   // XCD = n%8 heuristic
    const int it = n >> 4;
    const int i0 = it * 64;
    const int t  = threadIdx.x;
    const int w  = t >> 6;
    const int ln = t & 63;
    const int c  = ln & 15;
    const int g  = ln >> 4;

    const size_t slab = ((size_t)bh * 4 + g) * LL;
    const int i = i0 + w * 16 + c;

    const short8 qf = *(const short8*)(qb + (slab + i) * 8);   // pre-scaled q

    float4v o0 = {0.f, 0.f, 0.f, 0.f}, o1 = {0.f, 0.f, 0.f, 0.f};
    float dsum = 0.f;

    int t0 = it * 4 - 32; if (t0 < 0) t0 = 0;
    int t1 = it * 4 + 35; if (t1 > 255) t1 = 255;
    int tf0 = it * 4 - 28; if (tf0 < 0) tf0 = 0;
    int tf1 = it * 4 + 31; if (tf1 > 255) tf1 = 255;

    int ml[12], nm = 0;
    for (int tt = t0; tt < tf0; tt++) ml[nm++] = tt;
    for (int tt = tf1 + 1; tt <= t1; tt++) ml[nm++] = tt;
    const int gt[4] = {0, 3, 252, 255};
#pragma unroll
    for (int e = 0; e < 4; e++)
        if (gt[e] < t0 || gt[e] > t1) ml[nm++] = gt[e];

    const ushort* vb = vt + (size_t)bh * HD * LL;

    // ---- main mask-free loop ----
    const int npair_f = (tf1 - tf0 + 1) >> 1;
    const ushort* kp  = kb + (slab + (size_t)(tf0 * 16 + c)) * 8;
    const ushort* vp0 = vb + (size_t)c * LL + tf0 * 16 + g * 8;
    const ushort* vp1 = vp0 + 16 * LL;
    for (int m = 0; m < npair_f; m++) {
        const short8 kfA = *(const short8*)kp;
        const short8 kfB = *(const short8*)(kp + 128);
        kp += 256;
        float4v zero = {0.f, 0.f, 0.f, 0.f};
        float4v sA = __builtin_amdgcn_mfma_f32_16x16x32_bf16(kfA, qf, zero, 0, 0, 0);
        float4v sB = __builtin_amdgcn_mfma_f32_16x16x32_bf16(kfB, qf, zero, 0, 0, 0);

        float pA[4], pB[4];
#pragma unroll
        for (int r = 0; r < 4; r++) { pA[r] = rexp2(sA[r]); dsum += pA[r]; }
#pragma unroll
        for (int r = 0; r < 4; r++) { pB[r] = rexp2(sB[r]); dsum += pB[r]; }

        uint2 ua, ub2;
        ua.x  = pk2bf(pA[0], pA[1]);
        ua.y  = pk2bf(pA[2], pA[3]);
        ub2.x = pk2bf(pB[0], pB[1]);
        ub2.y = pk2bf(pB[2], pB[3]);
        const short8 pf = ptrans(ua, ub2, c, g);

        const short8 v0f = *(const short8*)vp0;
        const short8 v1f = *(const short8*)vp1;
        vp0 += 32; vp1 += 32;
        o0 = __builtin_amdgcn_mfma_f32_16x16x32_bf16(v0f, pf, o0, 0, 0, 0);
        o1 = __builtin_amdgcn_mfma_f32_16x16x32_bf16(v1f, pf, o1, 0, 0, 0);
    }

    // ---- masked epilogue (boundary + global-j tiles) ----
    for (int m = 0; m < nm; m += 2) {
        const int tA = ml[m], tB = ml[m + 1];
        const int gA = gcol_of(tA), gB = gcol_of(tB);
        const short8 kfA = *(const short8*)(kb + (slab + (size_t)(tA * 16 + c)) * 8);
        const short8 kfB = *(const short8*)(kb + (slab + (size_t)(tB * 16 + c)) * 8);
        float4v zero = {0.f, 0.f, 0.f, 0.f};
        float4v sA = __builtin_amdgcn_mfma_f32_16x16x32_bf16(kfA, qf, zero, 0, 0, 0);
        float4v sB = __builtin_amdgcn_mfma_f32_16x16x32_bf16(kfB, qf, zero, 0, 0, 0);

        float pA[4], pB[4];
#pragma unroll
        for (int r = 0; r < 4; r++) {
            int j = tA * 16 + g * 4 + r;
            bool ok = ((unsigned)(i - j + HALF_WIN) <= 2u * HALF_WIN) | (j == gA);
            pA[r] = ok ? rexp2(sA[r]) : 0.f;
            dsum += pA[r];
        }
#pragma unroll
        for (int r = 0; r < 4; r++) {
            int j = tB * 16 + g * 4 + r;
            bool ok = ((unsigned)(i - j + HALF_WIN) <= 2u * HALF_WIN) | (j == gB);
            pB[r] = ok ? rexp2(sB[r]) : 0.f;
            dsum += pB[r];
        }

        uint2 ua, ub2;
        ua.x  = pk2bf(pA[0], pA[1]);
        ua.y  = pk2bf(pA[2], pA[3]);
        ub2.x = pk2bf(pB[0], pB[1]);
        ub2.y = pk2bf(pB[2], pB[3]);
        const short8 pf = ptrans(ua, ub2, c, g);

        const int jv = (g < 2) ? tA * 16 + g * 8 : tB * 16 + (g - 2) * 8;
        const short8 v0f = *(const short8*)(vb + (size_t)c * LL + jv);
        const short8 v1f = *(const short8*)(vb + (size_t)(16 + c) * LL + jv);
        o0 = __builtin_amdgcn_mfma_f32_16x16x32_bf16(v0f, pf, o0, 0, 0, 0);
        o1 = __builtin_amdgcn_mfma_f32_16x16x32_bf16(v1f, pf, o1, 0, 0, 0);
    }

    // dsum: lane (c,g) holds partial for i=c over its j's; reduce across g
    dsum += __shfl_xor(dsum, 16);
    dsum += __shfl_xor(dsum, 32);
    const float inv = 1.0f / dsum;         // every reg of this lane has i=c

    // O^T layout: o0 reg r -> d = g*4+r, i = c;  o1 -> d = 16+g*4+r
    const int b = bh >> 3, hh = bh & 7;
    const size_t rowb = ((size_t)b * LL + i0 + w * 16 + c) * CC;
#pragma unroll
    for (int r = 0; r < 4; r++) {
        obuf[rowb + (size_t)(g * 4 + r) * 8 + hh]        = f2bf(o0[r] * inv);
        obuf[rowb + (size_t)(16 + g * 4 + r) * 8 + hh]   = f2bf(o1[r] * inv);
    }
}

// ---------------- Kernel 2b: global rows, j-split partials -------------------
__global__ __launch_bounds__(256) void attn_global_partial(const ushort* __restrict__ qb,
                                                           const ushort* __restrict__ kb,
                                                           const ushort* __restrict__ vt,
                                                           float* __restrict__ gpart) {
    __shared__ float qs[4][32];
    __shared__ float sc[4][256];
    const int ch = blockIdx.x;
    const int bh = blockIdx.y;
    const int t  = threadIdx.x;
    const int gidx[4] = {0, 63, LL - 64, LL - 1};

    if (t < 128) {
        int r = t >> 5, dd = t & 31;
        int i = gidx[r];
        qs[r][dd] = ubf(qb[(((size_t)bh * 4 + (dd >> 3)) * LL + i) * 8 + (dd & 7)]);
    }
    __syncthreads();

    const int j = ch * 256 + t;
    float dot[4] = {};
#pragma unroll
    for (int s = 0; s < 4; s++) {
        const short8 kf = *(const short8*)(kb + (((size_t)bh * 4 + s) * LL + j) * 8);
#pragma unroll
        for (int e = 0; e < 8; e++) {
            float kv = ubf((ushort)kf[e]);
#pragma unroll
            for (int r = 0; r < 4; r++) dot[r] += qs[r][s * 8 + e] * kv;
        }
    }
#pragma unroll
    for (int r = 0; r < 4; r++) sc[r][t] = rexp2(dot[r]);   // q pre-scaled
    __syncthreads();

    const int w = t >> 6, ln = t & 63;
    float den = sc[w][ln] + sc[w][ln + 64] + sc[w][ln + 128] + sc[w][ln + 192];
#pragma unroll
    for (int o = 1; o < 64; o <<= 1) den += __shfl_xor(den, o);

    const int dd = ln & 31, half = ln >> 5;
    float acc = 0.f;
    const ushort* vrow = vt + ((size_t)bh * HD + dd) * LL + ch * 256 + half * 128;
#pragma unroll
    for (int q8 = 0; q8 < 16; q8++) {
        const short8 v8 = *(const short8*)(vrow + q8 * 8);
#pragma unroll
        for (int e = 0; e < 8; e++) acc += sc[w][half * 128 + q8 * 8 + e] * ubf((ushort)v8[e]);
    }
    acc += __shfl_xor(acc, 32);

    float* gp = gpart + (((size_t)bh * 16 + ch) * 4 + w) * 33;
    if (ln < 32) gp[dd] = acc;
    if (ln == 0) gp[32] = den;
}

// ---------------- Kernel 2c: combine global-row partials ---------------------
__global__ __launch_bounds__(128) void attn_global_combine(const float* __restrict__ gpart,
                                                           ushort* __restrict__ obuf) {
    const int bh = blockIdx.x;
    const int t  = threadIdx.x;
    const int r  = t >> 5, dd = t & 31;
    const int gidx[4] = {0, 63, LL - 64, LL - 1};
    float pv = 0.f, den = 0.f;
#pragma unroll
    for (int ch = 0; ch < 16; ch++) {
        const float* gp = gpart + (((size_t)bh * 16 + ch) * 4 + r) * 33;
        pv  += gp[dd];
        den += gp[32];
    }
    const int b = bh >> 3, hh = bh & 7, i = gidx[r];
    obuf[((size_t)b * LL + i) * CC + dd * 8 + hh] = f2bf(pv / den);
}

// ---------------- Kernel 3: output projection (MFMA, zero-LDS) ---------------
__global__ __launch_bounds__(256) void proj_kernel(const ushort* __restrict__ obuf,
                                                   const ushort* __restrict__ w2t,
                                                   const float* __restrict__ b2,
                                                   float* __restrict__ out) {
    const int co0 = blockIdx.x * 16;
    const int l0  = blockIdx.y * 256 + (threadIdx.x >> 6) * 64;
    const int b   = blockIdx.z;
    const int ln  = threadIdx.x & 63;
    const int c   = ln & 15, g = ln >> 4;

    float4v acc[4] = {};
    const ushort* arow = w2t + (size_t)(co0 + c) * CC + g * 8;
    const ushort* brow = obuf + ((size_t)b * LL + l0 + c) * CC + g * 8;
#pragma unroll
    for (int ks = 0; ks < 8; ks++) {
        const short8 af = *(const short8*)(arow + ks * 32);
#pragma unroll
        for (int nf = 0; nf < 4; nf++) {
            const short8 bf = *(const short8*)(brow + (size_t)nf * 16 * CC + ks * 32);
            acc[nf] = __builtin_amdgcn_mfma_f32_16x16x32_bf16(af, bf, acc[nf], 0, 0, 0);
        }
    }
#pragma unroll
    for (int nf = 0; nf < 4; nf++) {
#pragma unroll
        for (int r = 0; r < 4; r++) {
            int co = co0 + g * 4 + r;
            int l  = l0 + nf * 16 + c;
            out[((size_t)b * CC + co) * LL + l] = acc[nf][r] + b2[co];
        }
    }
}

extern "C" void kernel_launch(void* const* d_in, const int* in_sizes, int n_in,
                              void* d_out, int out_size, void* d_ws, size_t ws_size,
                              hipStream_t stream) {
    const float* x  = (const float*)d_in[0];
    const float* w1 = (const float*)d_in[1];
    const float* b1 = (const float*)d_in[2];
    const float* w2 = (const float*)d_in[3];
    const float* b2 = (const float*)d_in[4];
    float* out = (float*)d_out;

    const size_t QKE = (size_t)BB * HEADS * LL * HD;
    const size_t OBE = (size_t)BB * LL * CC;
    ushort* qb  = (ushort*)d_ws;
    ushort* kb  = qb + QKE;
    ushort* vt  = kb + QKE;
    ushort* ob  = vt + QKE;
    float*  gp  = (float*)(ob + OBE);
    ushort* w2t = (ushort*)(gp + 16 * 16 * 4 * 33);
    ushort* w1t = w2t + CC * CC;

    wt_kernel<<<dim3(16, 64), 256, 0, stream>>>(w1, w2, w1t, w2t);
    qkv_kernel<<<dim3(4, 64, 2), 256, 0, stream>>>(x, w1t, b1, qb, kb, vt);
    attn_kernel<<<dim3(1024), 256, 0, stream>>>(qb, kb, vt, ob);
    attn_global_partial<<<dim3(16, 16), 256, 0, stream>>>(qb, kb, vt, gp);
    attn_global_combine<<<dim3(16), 128, 0, stream>>>(gp, ob);
    proj_kernel<<<dim3(16, 16, 2), 256, 0, stream>>>(ob, w2t, b2, out);
}

// Round 11
// 136.638 us; speedup vs baseline: 1.0915x; 1.0915x over previous
//
#include <hip/hip_runtime.h>
#include <hip/hip_bf16.h>

#define BB 2
#define CC 256
#define HEADS 8
#define HD 32
#define LL 4096
#define HALF_WIN 512

using short8  = __attribute__((ext_vector_type(8))) short;
using short4v = __attribute__((ext_vector_type(4))) short;
using float4v = __attribute__((ext_vector_type(4))) float;

__device__ __forceinline__ ushort f2bf(float x) {
    uint u = __float_as_uint(x);
    u += 0x7fff + ((u >> 16) & 1);
    return (ushort)(u >> 16);
}
__device__ __forceinline__ float ubf(ushort u) {
    return __uint_as_float((uint)u << 16);
}
// packed f32x2 -> bf16x2 (lo = first arg), HW instr on gfx950
__device__ __forceinline__ uint pk2bf(float a, float b) {
#if __has_builtin(__builtin_amdgcn_cvt_pk_bf16_f32)
    typedef __bf16 v2bf __attribute__((ext_vector_type(2)));
    union { v2bf v; uint u; } cv;
    cv.v = __builtin_amdgcn_cvt_pk_bf16_f32(a, b);
    return cv.u;
#else
    return (uint)f2bf(a) | ((uint)f2bf(b) << 16);
#endif
}
// raw v_exp_f32
__device__ __forceinline__ float rexp2(float x) {
#if __has_builtin(__builtin_amdgcn_exp2f)
    return __builtin_amdgcn_exp2f(x);
#else
    return exp2f(x);
#endif
}

// q is pre-scaled by (1/sqrt(32)) * log2(e) so attention uses exp2 directly
#define QSCALE 0.25503485f

// ---------------- Kernel 0: weight transpose + bf16 (w1 and w2) --------------
__global__ __launch_bounds__(256) void wt_kernel(const float* __restrict__ w1,
                                                 const float* __restrict__ w2,
                                                 ushort* __restrict__ w1t,
                                                 ushort* __restrict__ w2t) {
    __shared__ float tl[16][17];
    const int tx = threadIdx.x & 15, ty = threadIdx.x >> 4;
    const int ci0 = blockIdx.x * 16;
    const int y = blockIdx.y;
    if (y < 48) {
        int j0 = y * 16;
        tl[ty][tx] = w1[(size_t)(ci0 + ty) * 768 + j0 + tx];
        __syncthreads();
        w1t[(size_t)(j0 + ty) * CC + ci0 + tx] = f2bf(tl[tx][ty]);
    } else {
        int co0 = (y - 48) * 16;
        tl[ty][tx] = w2[(size_t)(ci0 + ty) * CC + co0 + tx];
        __syncthreads();
        w2t[(size_t)(co0 + ty) * CC + ci0 + tx] = f2bf(tl[tx][ty]);
    }
}

// ---------------- Kernel 1: QKV projection (MFMA) ----------------------------
__global__ __launch_bounds__(256) void qkv_kernel(const float* __restrict__ x,
                                                  const ushort* __restrict__ w1t,
                                                  const float* __restrict__ b1,
                                                  ushort* __restrict__ qb,
                                                  ushort* __restrict__ kb,
                                                  ushort* __restrict__ vt) {
    __shared__ __align__(16) ushort xs[64 * 264];  // [l][c]; reused in epilogue
    const int dg = blockIdx.x;
    const int l0 = blockIdx.y * 64;
    const int b  = blockIdx.z;
    const int t  = threadIdx.x;
    const int w  = t >> 6, ln = t & 63, c = ln & 15, g = ln >> 4;

    {
        const int l  = t & 63;
        const int cg = (t >> 6) * 4;
#pragma unroll
        for (int p = 0; p < 16; p++) {
            int c0 = p * 16 + cg;
            float a0 = x[((size_t)b * CC + c0 + 0) * LL + l0 + l];
            float a1 = x[((size_t)b * CC + c0 + 1) * LL + l0 + l];
            float a2 = x[((size_t)b * CC + c0 + 2) * LL + l0 + l];
            float a3 = x[((size_t)b * CC + c0 + 3) * LL + l0 + l];
            uint2 u;
            u.x = pk2bf(a0, a1);
            u.y = pk2bf(a2, a3);
            *(uint2*)&xs[l * 264 + c0] = u;
        }
    }
    __syncthreads();

    const int jbase = dg * 192 + w * 48;
    float4v acc[3][4] = {};
#pragma unroll
    for (int ks = 0; ks < 8; ks++) {
        short8 af[3], bfr[4];
#pragma unroll
        for (int jt = 0; jt < 3; jt++)
            af[jt] = *(const short8*)(w1t + (size_t)(jbase + jt * 16 + c) * CC + ks * 32 + g * 8);
#pragma unroll
        for (int lt = 0; lt < 4; lt++)
            bfr[lt] = *(const short8*)&xs[(lt * 16 + c) * 264 + ks * 32 + g * 8];
#pragma unroll
        for (int jt = 0; jt < 3; jt++)
#pragma unroll
            for (int lt = 0; lt < 4; lt++)
                acc[jt][lt] = __builtin_amdgcn_mfma_f32_16x16x32_bf16(af[jt], bfr[lt], acc[jt][lt], 0, 0, 0);
    }
    __syncthreads();

    ushort* qs  = xs;
    ushort* ksm = xs + 64 * 72;
    ushort* vs  = xs + 2 * 64 * 72;

#pragma unroll
    for (int jt = 0; jt < 3; jt++) {
#pragma unroll
        for (int r = 0; r < 4; r++) {
            int j = jbase + jt * 16 + g * 4 + r;
            float bias = b1[j];
            int t3 = j % 3, h = (j / 3) & 7, dl = (j / 24) & 7;
            int slot = h * 8 + dl;
            float v0 = acc[jt][0][r] + bias;
            float v1 = acc[jt][1][r] + bias;
            float v2 = acc[jt][2][r] + bias;
            float v3 = acc[jt][3][r] + bias;
            if (t3 == 0) { v0 *= QSCALE; v1 *= QSCALE; v2 *= QSCALE; v3 *= QSCALE; }
            uint u01 = pk2bf(v0, v1);
            uint u23 = pk2bf(v2, v3);
            ushort* dst = (t3 == 0) ? qs : (t3 == 1) ? ksm : vs;
            int stride = (t3 == 2) ? 74 : 72;
            dst[(0 * 16 + c) * stride + slot] = (ushort)u01;
            dst[(1 * 16 + c) * stride + slot] = (ushort)(u01 >> 16);
            dst[(2 * 16 + c) * stride + slot] = (ushort)u23;
            dst[(3 * 16 + c) * stride + slot] = (ushort)(u23 >> 16);
        }
    }
    __syncthreads();

    {
        const int l = t & 63;
#pragma unroll
        for (int p = 0; p < 2; p++) {
            int h = p * 4 + (t >> 6);
            size_t rowq = (((size_t)(b * 8 + h) * 4 + dg) * LL + l0 + l) * 8;
            *(short8*)(qb + rowq) = *(const short8*)&qs[l * 72 + h * 8];
            *(short8*)(kb + rowq) = *(const short8*)&ksm[l * 72 + h * 8];
        }
#pragma unroll
        for (int p = 0; p < 16; p++) {
            int hd = p * 4 + (t >> 6);
            vt[((size_t)(b * 8 + (hd >> 3)) * HD + dg * 8 + (hd & 7)) * LL + l0 + l] = vs[l * 74 + hd];
        }
    }
}

__device__ __forceinline__ int gcol_of(int tt) {
    return (tt == 0) ? 0 : (tt == 3) ? 63 : (tt == 252) ? LL - 64 : (tt == 255) ? LL - 1 : -1;
}

// ---------------- Kernel 2: banded MFMA attention ----------------------------
// Waves split the j-range (not i): each wave owns 1/4 of the band pairs and
// processes all 4 i-subtiles per iter (4x fewer K/V loads per block, 4x more
// independent work per load). Partials combined across waves via LDS once.
__global__ __launch_bounds__(256, 4) void attn_kernel(const ushort* __restrict__ qb,
                                                      const ushort* __restrict__ kb,
                                                      const ushort* __restrict__ vt,
                                                      ushort* __restrict__ obuf) {
    __shared__ __align__(16) ushort pshare[4][4][576];  // [wave][subtile], 36-stride rows
    __shared__ float cbuf[4][3][64][9];                 // [subtile][other-wave][lane]{o0,o1,ds}
    const int n  = blockIdx.x;
    const int bh = ((n & 7) << 1) | ((n >> 3) & 1);     // XCD = n%8 heuristic
    const int it = n >> 4;
    const int i0 = it * 64;
    const int t  = threadIdx.x;
    const int w  = t >> 6;
    const int ln = t & 63;
    const int c  = ln & 15;
    const int g  = ln >> 4;

    const size_t slab = ((size_t)bh * 4 + g) * LL;

    short8 qf[4];
#pragma unroll
    for (int s = 0; s < 4; s++)
        qf[s] = *(const short8*)(qb + (slab + i0 + s * 16 + c) * 8);   // pre-scaled q

    float4v o0[4], o1[4];
#pragma unroll
    for (int s = 0; s < 4; s++) {
#pragma unroll
        for (int r = 0; r < 4; r++) { o0[s][r] = 0.f; o1[s][r] = 0.f; }
    }
    float dsum[4] = {0.f, 0.f, 0.f, 0.f};

    int t0 = it * 4 - 32; if (t0 < 0) t0 = 0;
    int t1 = it * 4 + 35; if (t1 > 255) t1 = 255;
    int tf0 = it * 4 - 28; if (tf0 < 0) tf0 = 0;
    int tf1 = it * 4 + 31; if (tf1 > 255) tf1 = 255;

    int ml[12], nm = 0;
    for (int tt = t0; tt < tf0; tt++) ml[nm++] = tt;
    for (int tt = tf1 + 1; tt <= t1; tt++) ml[nm++] = tt;
    const int gt[4] = {0, 3, 252, 255};
#pragma unroll
    for (int e = 0; e < 4; e++)
        if (gt[e] < t0 || gt[e] > t1) ml[nm++] = gt[e];

    const ushort* vb = vt + (size_t)bh * HD * LL;
    ushort* wbb = &pshare[w][0][0];

    // ---- band pairs: contiguous quarter per wave ----
    const int npair_f = (tf1 - tf0 + 1) >> 1;
    const int qq = npair_f >> 2, rem = npair_f & 3;
    const int mstart = w * qq + (w < rem ? w : rem);
    const int mcount = qq + (w < rem ? 1 : 0);
    const int tfs = tf0 + 2 * mstart;

    const ushort* kp  = kb + (slab + (size_t)(tfs * 16 + c)) * 8;
    const ushort* vp0 = vb + (size_t)c * LL + tfs * 16 + g * 8;
    const ushort* vp1 = vp0 + 16 * LL;
    for (int m = 0; m < mcount; m++) {
        const short8 kfA = *(const short8*)kp;
        const short8 kfB = *(const short8*)(kp + 128);
        kp += 256;
        const short8 v0f = *(const short8*)vp0;
        const short8 v1f = *(const short8*)vp1;
        vp0 += 32; vp1 += 32;
        float4v zero = {0.f, 0.f, 0.f, 0.f};
#pragma unroll
        for (int s = 0; s < 4; s++) {
            float4v sA = __builtin_amdgcn_mfma_f32_16x16x32_bf16(kfA, qf[s], zero, 0, 0, 0);
            float4v sB = __builtin_amdgcn_mfma_f32_16x16x32_bf16(kfB, qf[s], zero, 0, 0, 0);
            float pA[4], pB[4];
#pragma unroll
            for (int r = 0; r < 4; r++) { pA[r] = rexp2(sA[r]); dsum[s] += pA[r]; }
#pragma unroll
            for (int r = 0; r < 4; r++) { pB[r] = rexp2(sB[r]); dsum[s] += pB[r]; }
            uint2 ua, ub2;
            ua.x  = pk2bf(pA[0], pA[1]);
            ua.y  = pk2bf(pA[2], pA[3]);
            ub2.x = pk2bf(pB[0], pB[1]);
            ub2.y = pk2bf(pB[2], pB[3]);
            ushort* wb = wbb + s * 576;
            *(uint2*)&wb[c * 36 + 4 * g]      = ua;
            *(uint2*)&wb[c * 36 + 16 + 4 * g] = ub2;
        }
#pragma unroll
        for (int s = 0; s < 4; s++) {
            const ushort* wb = wbb + s * 576;
            union { short8 s8; short4v s4[2]; } pu;
            pu.s4[0] = *(const short4v*)&wb[c * 36 + 8 * g];
            pu.s4[1] = *(const short4v*)&wb[c * 36 + 8 * g + 4];
            o0[s] = __builtin_amdgcn_mfma_f32_16x16x32_bf16(pu.s8, v0f, o0[s], 0, 0, 0);
            o1[s] = __builtin_amdgcn_mfma_f32_16x16x32_bf16(pu.s8, v1f, o1[s], 0, 0, 0);
        }
    }

    // ---- masked pairs: round-robin over waves ----
    for (int p = 0; p < (nm >> 1); p++) {
        if ((p & 3) != w) continue;
        const int tA = ml[2 * p], tB = ml[2 * p + 1];
        const int gA = gcol_of(tA), gB = gcol_of(tB);
        const short8 kfA = *(const short8*)(kb + (slab + (size_t)(tA * 16 + c)) * 8);
        const short8 kfB = *(const short8*)(kb + (slab + (size_t)(tB * 16 + c)) * 8);
        const int jv = (g < 2) ? tA * 16 + g * 8 : tB * 16 + (g - 2) * 8;
        const short8 v0f = *(const short8*)(vb + (size_t)c * LL + jv);
        const short8 v1f = *(const short8*)(vb + (size_t)(16 + c) * LL + jv);
        float4v zero = {0.f, 0.f, 0.f, 0.f};
#pragma unroll
        for (int s = 0; s < 4; s++) {
            const int i = i0 + s * 16 + c;
            float4v sA = __builtin_amdgcn_mfma_f32_16x16x32_bf16(kfA, qf[s], zero, 0, 0, 0);
            float4v sB = __builtin_amdgcn_mfma_f32_16x16x32_bf16(kfB, qf[s], zero, 0, 0, 0);
            float pA[4], pB[4];
#pragma unroll
            for (int r = 0; r < 4; r++) {
                int j = tA * 16 + g * 4 + r;
                bool ok = ((unsigned)(i - j + HALF_WIN) <= 2u * HALF_WIN) | (j == gA);
                pA[r] = ok ? rexp2(sA[r]) : 0.f;
                dsum[s] += pA[r];
            }
#pragma unroll
            for (int r = 0; r < 4; r++) {
                int j = tB * 16 + g * 4 + r;
                bool ok = ((unsigned)(i - j + HALF_WIN) <= 2u * HALF_WIN) | (j == gB);
                pB[r] = ok ? rexp2(sB[r]) : 0.f;
                dsum[s] += pB[r];
            }
            uint2 ua, ub2;
            ua.x  = pk2bf(pA[0], pA[1]);
            ua.y  = pk2bf(pA[2], pA[3]);
            ub2.x = pk2bf(pB[0], pB[1]);
            ub2.y = pk2bf(pB[2], pB[3]);
            ushort* wb = wbb + s * 576;
            *(uint2*)&wb[c * 36 + 4 * g]      = ua;
            *(uint2*)&wb[c * 36 + 16 + 4 * g] = ub2;
        }
#pragma unroll
        for (int s = 0; s < 4; s++) {
            const ushort* wb = wbb + s * 576;
            union { short8 s8; short4v s4[2]; } pu;
            pu.s4[0] = *(const short4v*)&wb[c * 36 + 8 * g];
            pu.s4[1] = *(const short4v*)&wb[c * 36 + 8 * g + 4];
            o0[s] = __builtin_amdgcn_mfma_f32_16x16x32_bf16(pu.s8, v0f, o0[s], 0, 0, 0);
            o1[s] = __builtin_amdgcn_mfma_f32_16x16x32_bf16(pu.s8, v1f, o1[s], 0, 0, 0);
        }
    }

    // ---- cross-wave combine: wave w finalizes subtile w ----
#pragma unroll
    for (int s = 0; s < 4; s++) {
        if (s == w) continue;
        float* cb = &cbuf[s][(w < s) ? w : w - 1][ln][0];
#pragma unroll
        for (int r = 0; r < 4; r++) { cb[r] = o0[s][r]; cb[4 + r] = o1[s][r]; }
        cb[8] = dsum[s];
    }
    __syncthreads();

    float4v O0 = o0[w], O1 = o1[w];
    float ds = dsum[w];
#pragma unroll
    for (int k = 0; k < 3; k++) {
        const float* cb = &cbuf[w][k][ln][0];
#pragma unroll
        for (int r = 0; r < 4; r++) { O0[r] += cb[r]; O1[r] += cb[4 + r]; }
        ds += cb[8];
    }

    ds += __shfl_xor(ds, 16);
    ds += __shfl_xor(ds, 32);

    const int b = bh >> 3, hh = bh & 7;
#pragma unroll
    for (int r = 0; r < 4; r++) {
        float dn = __shfl(ds, g * 4 + r);
        float inv = 1.0f / dn;
        int irow = i0 + w * 16 + g * 4 + r;
        size_t rowb = ((size_t)b * LL + irow) * CC;
        obuf[rowb + (size_t)c * 8 + hh]        = f2bf(O0[r] * inv);
        obuf[rowb + (size_t)(16 + c) * 8 + hh] = f2bf(O1[r] * inv);
    }
}

// ---------------- Kernel 2b: global rows, j-split partials -------------------
__global__ __launch_bounds__(256) void attn_global_partial(const ushort* __restrict__ qb,
                                                           const ushort* __restrict__ kb,
                                                           const ushort* __restrict__ vt,
                                                           float* __restrict__ gpart) {
    __shared__ float qs[4][32];
    __shared__ float sc[4][256];
    const int ch = blockIdx.x;
    const int bh = blockIdx.y;
    const int t  = threadIdx.x;
    const int gidx[4] = {0, 63, LL - 64, LL - 1};

    if (t < 128) {
        int r = t >> 5, dd = t & 31;
        int i = gidx[r];
        qs[r][dd] = ubf(qb[(((size_t)bh * 4 + (dd >> 3)) * LL + i) * 8 + (dd & 7)]);
    }
    __syncthreads();

    const int j = ch * 256 + t;
    float dot[4] = {};
#pragma unroll
    for (int s = 0; s < 4; s++) {
        const short8 kf = *(const short8*)(kb + (((size_t)bh * 4 + s) * LL + j) * 8);
#pragma unroll
        for (int e = 0; e < 8; e++) {
            float kv = ubf((ushort)kf[e]);
#pragma unroll
            for (int r = 0; r < 4; r++) dot[r] += qs[r][s * 8 + e] * kv;
        }
    }
#pragma unroll
    for (int r = 0; r < 4; r++) sc[r][t] = rexp2(dot[r]);   // q pre-scaled
    __syncthreads();

    const int w = t >> 6, ln = t & 63;
    float den = sc[w][ln] + sc[w][ln + 64] + sc[w][ln + 128] + sc[w][ln + 192];
#pragma unroll
    for (int o = 1; o < 64; o <<= 1) den += __shfl_xor(den, o);

    const int dd = ln & 31, half = ln >> 5;
    float acc = 0.f;
    const ushort* vrow = vt + ((size_t)bh * HD + dd) * LL + ch * 256 + half * 128;
#pragma unroll
    for (int q8 = 0; q8 < 16; q8++) {
        const short8 v8 = *(const short8*)(vrow + q8 * 8);
#pragma unroll
        for (int e = 0; e < 8; e++) acc += sc[w][half * 128 + q8 * 8 + e] * ubf((ushort)v8[e]);
    }
    acc += __shfl_xor(acc, 32);

    float* gp = gpart + (((size_t)bh * 16 + ch) * 4 + w) * 33;
    if (ln < 32) gp[dd] = acc;
    if (ln == 0) gp[32] = den;
}

// ---------------- Kernel 2c: combine global-row partials ---------------------
__global__ __launch_bounds__(128) void attn_global_combine(const float* __restrict__ gpart,
                                                           ushort* __restrict__ obuf) {
    const int bh = blockIdx.x;
    const int t  = threadIdx.x;
    const int r  = t >> 5, dd = t & 31;
    const int gidx[4] = {0, 63, LL - 64, LL - 1};
    float pv = 0.f, den = 0.f;
#pragma unroll
    for (int ch = 0; ch < 16; ch++) {
        const float* gp = gpart + (((size_t)bh * 16 + ch) * 4 + r) * 33;
        pv  += gp[dd];
        den += gp[32];
    }
    const int b = bh >> 3, hh = bh & 7, i = gidx[r];
    obuf[((size_t)b * LL + i) * CC + dd * 8 + hh] = f2bf(pv / den);
}

// ---------------- Kernel 3: output projection (MFMA, zero-LDS) ---------------
__global__ __launch_bounds__(256) void proj_kernel(const ushort* __restrict__ obuf,
                                                   const ushort* __restrict__ w2t,
                                                   const float* __restrict__ b2,
                                                   float* __restrict__ out) {
    const int co0 = blockIdx.x * 16;
    const int l0  = blockIdx.y * 256 + (threadIdx.x >> 6) * 64;
    const int b   = blockIdx.z;
    const int ln  = threadIdx.x & 63;
    const int c   = ln & 15, g = ln >> 4;

    float4v acc[4] = {};
    const ushort* arow = w2t + (size_t)(co0 + c) * CC + g * 8;
    const ushort* brow = obuf + ((size_t)b * LL + l0 + c) * CC + g * 8;
#pragma unroll
    for (int ks = 0; ks < 8; ks++) {
        const short8 af = *(const short8*)(arow + ks * 32);
#pragma unroll
        for (int nf = 0; nf < 4; nf++) {
            const short8 bf = *(const short8*)(brow + (size_t)nf * 16 * CC + ks * 32);
            acc[nf] = __builtin_amdgcn_mfma_f32_16x16x32_bf16(af, bf, acc[nf], 0, 0, 0);
        }
    }
#pragma unroll
    for (int nf = 0; nf < 4; nf++) {
#pragma unroll
        for (int r = 0; r < 4; r++) {
            int co = co0 + g * 4 + r;
            int l  = l0 + nf * 16 + c;
            out[((size_t)b * CC + co) * LL + l] = acc[nf][r] + b2[co];
        }
    }
}

extern "C" void kernel_launch(void* const* d_in, const int* in_sizes, int n_in,
                              void* d_out, int out_size, void* d_ws, size_t ws_size,
                              hipStream_t stream) {
    const float* x  = (const float*)d_in[0];
    const float* w1 = (const float*)d_in[1];
    const float* b1 = (const float*)d_in[2];
    const float* w2 = (const float*)d_in[3];
    const float* b2 = (const float*)d_in[4];
    float* out = (float*)d_out;

    const size_t QKE = (size_t)BB * HEADS * LL * HD;
    const size_t OBE = (size_t)BB * LL * CC;
    ushort* qb  = (ushort*)d_ws;
    ushort* kb  = qb + QKE;
    ushort* vt  = kb + QKE;
    ushort* ob  = vt + QKE;
    float*  gp  = (float*)(ob + OBE);
    ushort* w2t = (ushort*)(gp + 16 * 16 * 4 * 33);
    ushort* w1t = w2t + CC * CC;

    wt_kernel<<<dim3(16, 64), 256, 0, stream>>>(w1, w2, w1t, w2t);
    qkv_kernel<<<dim3(4, 64, 2), 256, 0, stream>>>(x, w1t, b1, qb, kb, vt);
    attn_kernel<<<dim3(1024), 256, 0, stream>>>(qb, kb, vt, ob);
    attn_global_partial<<<dim3(16, 16), 256, 0, stream>>>(qb, kb, vt, gp);
    attn_global_combine<<<dim3(16), 128, 0, stream>>>(gp, ob);
    proj_kernel<<<dim3(16, 16, 2), 256, 0, stream>>>(ob, w2t, b2, out);
}